// Round 4
// baseline (335.488 us; speedup 1.0000x reference)
//
#include <hip/hip_runtime.h>

// ---------------------------------------------------------------------------
// WaveSubsystem fused:
//   out = tanh(c@W_mod + b_mod) * (w @ M) + [c z]@W_B + b_B
//   M^T = diag(tanh(A_diag)*0.9) + A_U@A_V^T   (tiny GEMM, bf16)
// Round 4: 128x64 tiles -> 1024 blocks = 4 blocks/CU resident (was 512 = 2/CU,
// grid-capped occupancy; barrier drains un-hideable). Prologue merged to one
// prep kernel. XOR-swizzled LDS retained (conflicts measured 0).
// ---------------------------------------------------------------------------

#define DEV __device__ __forceinline__

typedef __bf16 v8bf __attribute__((ext_vector_type(8)));
typedef __bf16 v4bf __attribute__((ext_vector_type(4)));
typedef float  v4f  __attribute__((ext_vector_type(4)));

typedef __attribute__((address_space(1))) const unsigned int* as1_cuint_ptr;
typedef __attribute__((address_space(3))) unsigned int*       as3_uint_ptr;

DEV void async16(const void* g, void* l) {
  __builtin_amdgcn_global_load_lds(
      (as1_cuint_ptr)(unsigned long long)g,
      (as3_uint_ptr)(unsigned long long)l,
      16, 0, 0);
}

DEV float tanh_fast(float x) {
  x = fminf(15.f, fmaxf(-15.f, x));
  float e = __expf(2.f * x);
  return (e - 1.f) / (e + 1.f);
}

// --------------------------- prep kernel -----------------------------------
// Blocks 0..22527: f32->bf16 convert (w 8192, z 8192, c 4096, A_U 1024,
// A_V 1024; 1024 elts/block). Blocks 22528..30719: 32x32 transpose-convert
// tiles (W_mod 2048 tiles, W_B 6144 tiles).
__global__ void prep(const float* __restrict__ w, const float* __restrict__ z,
                     const float* __restrict__ c, const float* __restrict__ au,
                     const float* __restrict__ av,
                     const float* __restrict__ Wmod, const float* __restrict__ WB,
                     __bf16* __restrict__ wb, __bf16* __restrict__ zb,
                     __bf16* __restrict__ cb, __bf16* __restrict__ aub,
                     __bf16* __restrict__ avb,
                     __bf16* __restrict__ Wmodt, __bf16* __restrict__ WBt) {
  __shared__ float t[32][33];
  int b = blockIdx.x;
  if (b < 22528) {
    const float* src; __bf16* dst; int off;
    if (b < 8192)        { src = w;  dst = wb;  off = b; }
    else if (b < 16384)  { src = z;  dst = zb;  off = b - 8192; }
    else if (b < 20480)  { src = c;  dst = cb;  off = b - 16384; }
    else if (b < 21504)  { src = au; dst = aub; off = b - 20480; }
    else                 { src = av; dst = avb; off = b - 21504; }
    size_t i = (size_t)off * 1024 + (size_t)threadIdx.x * 4;
    float4 v = *reinterpret_cast<const float4*>(src + i);
    v4bf o;
    o.x = (__bf16)v.x; o.y = (__bf16)v.y; o.z = (__bf16)v.z; o.w = (__bf16)v.w;
    *reinterpret_cast<v4bf*>(dst + i) = o;
    return;
  }
  b -= 22528;
  const float* src; __bf16* dst; int R;
  if (b < 2048) { src = Wmod; dst = Wmodt; R = 1024; }
  else          { b -= 2048; src = WB; dst = WBt; R = 3072; }
  const int c0 = (b & 63) * 32, r0 = (b >> 6) * 32;
  const int C = 2048;
  const int tx = threadIdx.x & 31, ty = threadIdx.x >> 5;
#pragma unroll
  for (int rr = 0; rr < 32; rr += 8)
    t[ty + rr][tx] = src[(size_t)(r0 + ty + rr) * C + c0 + tx];
  __syncthreads();
#pragma unroll
  for (int rr = 0; rr < 32; rr += 8)
    dst[(size_t)(c0 + ty + rr) * R + r0 + tx] = (__bf16)t[tx][ty + rr];
}

// ---------------------- Mt builder GEMM ------------------------------------
// Mt[m][n'] = (A_U @ A_V^T)[m][n'] + (m==n' ? tanh(A_diag[m])*0.9 : 0)
__global__ __launch_bounds__(256, 2) void gemm_mt(
    const __bf16* __restrict__ A0, const __bf16* __restrict__ Bt,
    int N, int K, __bf16* __restrict__ out, const float* __restrict__ A_diag) {
  __shared__ __align__(16) __bf16 As[128 * 32];
  __shared__ __align__(16) __bf16 Bs[128 * 32];

  const int tid = threadIdx.x, lane = tid & 63, wid = tid >> 6;
  const int wm = wid >> 1, wn = wid & 1, l16 = lane & 15, quad = lane >> 4;
  const int m0 = blockIdx.y * 128, n0 = blockIdx.x * 128;
  const int sg_row = lane >> 2;
  const int sk = ((lane & 3) ^ ((lane >> 3) & 3)) * 8;
  const int qs = quad ^ ((l16 >> 1) & 3);

  v4f acc[4][4];
#pragma unroll
  for (int i = 0; i < 4; ++i)
#pragma unroll
    for (int j = 0; j < 4; ++j) { v4f zz = {0,0,0,0}; acc[i][j] = zz; }

  for (int k0 = 0; k0 < K; k0 += 32) {
    __syncthreads();
#pragma unroll
    for (int t = 0; t < 2; ++t) {
      const int chunk = wid * 2 + t;
      const int row = chunk * 16 + sg_row;
      async16((const void*)(A0 + (size_t)(m0 + row) * K + k0 + sk),
              (void*)&As[chunk * 512 + lane * 8]);
      async16((const void*)(Bt + (size_t)(n0 + row) * K + k0 + sk),
              (void*)&Bs[chunk * 512 + lane * 8]);
    }
    __syncthreads();
    const v8bf* Ap = reinterpret_cast<const v8bf*>(As);
    const v8bf* Bp = reinterpret_cast<const v8bf*>(Bs);
    v8bf a[4], b[4];
#pragma unroll
    for (int i = 0; i < 4; ++i) a[i] = Ap[(wm * 64 + i * 16 + l16) * 4 + qs];
#pragma unroll
    for (int j = 0; j < 4; ++j) b[j] = Bp[(wn * 64 + j * 16 + l16) * 4 + qs];
#pragma unroll
    for (int i = 0; i < 4; ++i)
#pragma unroll
      for (int j = 0; j < 4; ++j)
        acc[i][j] = __builtin_amdgcn_mfma_f32_16x16x32_bf16(a[i], b[j],
                                                            acc[i][j], 0, 0, 0);
  }

  const int mBase = m0 + wm * 64 + quad * 4;
  const int nBase = n0 + wn * 64 + l16;
#pragma unroll
  for (int j = 0; j < 4; ++j) {
    const int n = nBase + j * 16;
#pragma unroll
    for (int i = 0; i < 4; ++i)
#pragma unroll
      for (int r = 0; r < 4; ++r) {
        const int m = mBase + i * 16 + r;
        float v = acc[i][j][r];
        if (m == n) v += tanh_fast(A_diag[m]) * 0.9f;
        out[(size_t)m * N + n] = (__bf16)v;
      }
  }
}

// ---------------------- fused main kernel ----------------------------------
// 128(m) x 64(n) tile; 4 waves in 2x2 (each 64m x 32n, acc[4][2]).
// Grid 32x32 = 1024 blocks -> 4 blocks/CU resident.
__global__ __launch_bounds__(256, 4) void fused_main(
    const __bf16* __restrict__ c, const __bf16* __restrict__ z,
    const __bf16* __restrict__ w, const __bf16* __restrict__ Wmodt,
    const __bf16* __restrict__ Mt, const __bf16* __restrict__ WBt,
    const float* __restrict__ b_mod, const float* __restrict__ b_B,
    float* __restrict__ out) {
  constexpr int DC = 1024, DW = 2048, KB = 3072;
  __shared__ __align__(16) __bf16 As[128 * 32];  // 8 KB
  __shared__ __align__(16) __bf16 Bs[64 * 32];   // 4 KB

  const int tid = threadIdx.x, lane = tid & 63, wid = tid >> 6;
  const int wm = wid >> 1, wn = wid & 1, l16 = lane & 15, quad = lane >> 4;
  const int m0 = blockIdx.y * 128;  // batch
  const int n0 = blockIdx.x * 64;   // d_w
  const int sg_row = lane >> 2;
  const int sk = ((lane & 3) ^ ((lane >> 3) & 3)) * 8;  // staging swizzle
  const int qs = quad ^ ((l16 >> 1) & 3);               // read swizzle
  const int rowA0 = wid * 32 + sg_row;
  const int rowA1 = wid * 32 + 16 + sg_row;
  const int rowB  = wid * 16 + sg_row;
  const int ldsA0 = (wid * 2) * 512 + lane * 8;
  const int ldsA1 = (wid * 2 + 1) * 512 + lane * 8;
  const int ldsB  = wid * 512 + lane * 8;

  v4f acc[4][2];
#pragma unroll
  for (int i = 0; i < 4; ++i)
#pragma unroll
    for (int j = 0; j < 2; ++j) { v4f zz = {0,0,0,0}; acc[i][j] = zz; }

  auto kstep = [&](const __bf16* gA, size_t lda, const __bf16* gB, size_t ldb,
                   int kA, int kB) {
    __syncthreads();
    async16((const void*)(gA + (size_t)(m0 + rowA0) * lda + kA + sk),
            (void*)&As[ldsA0]);
    async16((const void*)(gA + (size_t)(m0 + rowA1) * lda + kA + sk),
            (void*)&As[ldsA1]);
    async16((const void*)(gB + (size_t)(n0 + rowB) * ldb + kB + sk),
            (void*)&Bs[ldsB]);
    __syncthreads();
    const v8bf* Ap = reinterpret_cast<const v8bf*>(As);
    const v8bf* Bp = reinterpret_cast<const v8bf*>(Bs);
    v8bf a[4], b[2];
#pragma unroll
    for (int i = 0; i < 4; ++i) a[i] = Ap[(wm * 64 + i * 16 + l16) * 4 + qs];
#pragma unroll
    for (int j = 0; j < 2; ++j) b[j] = Bp[(wn * 32 + j * 16 + l16) * 4 + qs];
#pragma unroll
    for (int i = 0; i < 4; ++i)
#pragma unroll
      for (int j = 0; j < 2; ++j)
        acc[i][j] = __builtin_amdgcn_mfma_f32_16x16x32_bf16(a[i], b[j],
                                                            acc[i][j], 0, 0, 0);
  };

  const int nBase = n0 + wn * 32 + l16;

  // ---- phase A: mod = tanh(c @ Wmodt + b_mod) ----
  for (int k0 = 0; k0 < DC; k0 += 32) kstep(c, DC, Wmodt, DC, k0, k0);

  v4f mod_s[4][2];
#pragma unroll
  for (int j = 0; j < 2; ++j) {
    const float bn = b_mod[nBase + j * 16];
#pragma unroll
    for (int i = 0; i < 4; ++i) {
#pragma unroll
      for (int r = 0; r < 4; ++r)
        mod_s[i][j][r] = tanh_fast(acc[i][j][r] + bn);
      v4f zz = {0,0,0,0};
      acc[i][j] = zz;
    }
  }

  // ---- phase B: acc = w @ Mt ----
  for (int k0 = 0; k0 < DW; k0 += 32) kstep(w, DW, Mt, DW, k0, k0);

#pragma unroll
  for (int i = 0; i < 4; ++i)
#pragma unroll
    for (int j = 0; j < 2; ++j) acc[i][j] *= mod_s[i][j];

  // ---- phase C: acc += [c z] @ WBt ----
  for (int k0 = 0; k0 < DC; k0 += 32) kstep(c, DC, WBt, KB, k0, k0);
  for (int k0 = DC; k0 < KB; k0 += 32) kstep(z, DW, WBt, KB, k0 - DC, k0);

  // ---- epilogue ----
  const int mBase = m0 + wm * 64 + quad * 4;
#pragma unroll
  for (int j = 0; j < 2; ++j) {
    const int n = nBase + j * 16;
    const float bn = b_B[n];
#pragma unroll
    for (int i = 0; i < 4; ++i)
#pragma unroll
      for (int r = 0; r < 4; ++r) {
        const int m = mBase + i * 16 + r;
        out[(size_t)m * DW + n] = acc[i][j][r] + bn;
      }
  }
}

// ------------------------------ launch -------------------------------------

extern "C" void kernel_launch(void* const* d_in, const int* in_sizes, int n_in,
                              void* d_out, int out_size, void* d_ws,
                              size_t ws_size, hipStream_t stream) {
  const float* w_prev = (const float*)d_in[0];
  const float* z_t    = (const float*)d_in[1];
  const float* c_t    = (const float*)d_in[2];
  const float* A_diag = (const float*)d_in[3];
  const float* A_U    = (const float*)d_in[4];
  const float* A_V    = (const float*)d_in[5];
  const float* W_mod  = (const float*)d_in[6];
  const float* b_mod  = (const float*)d_in[7];
  const float* W_B    = (const float*)d_in[8];
  const float* b_B    = (const float*)d_in[9];

  constexpr int Bsz = 4096, DW = 2048, RK = 512;
  const size_t MB = 1ull << 20;
  char* ws = (char*)d_ws;
  __bf16* w_bf  = (__bf16*)(ws + 0);        // 16 MB
  __bf16* z_bf  = (__bf16*)(ws + 16 * MB);  // 16 MB
  __bf16* c_bf  = (__bf16*)(ws + 32 * MB);  //  8 MB
  __bf16* AU_bf = (__bf16*)(ws + 40 * MB);  //  2 MB  [2048][512]
  __bf16* AV_bf = (__bf16*)(ws + 42 * MB);  //  2 MB  [2048][512]
  __bf16* Wmodt = (__bf16*)(ws + 44 * MB);  //  4 MB  [2048][1024]
  __bf16* WBt   = (__bf16*)(ws + 48 * MB);  // 12 MB  [2048][3072]
  __bf16* Mt    = (__bf16*)(ws + 60 * MB);  //  8 MB  [2048][2048]

  prep<<<30720, 256, 0, stream>>>(w_prev, z_t, c_t, A_U, A_V, W_mod, W_B,
                                  w_bf, z_bf, c_bf, AU_bf, AV_bf, Wmodt, WBt);

  gemm_mt<<<dim3(DW / 128, DW / 128), 256, 0, stream>>>(AU_bf, AV_bf, DW, RK,
                                                        Mt, A_diag);

  fused_main<<<dim3(DW / 64, Bsz / 128), 256, 0, stream>>>(
      c_bf, z_bf, w_bf, Wmodt, Mt, WBt, b_mod, b_B, (float*)d_out);
}

// Round 5
// 289.095 us; speedup vs baseline: 1.1605x; 1.1605x over previous
//
#include <hip/hip_runtime.h>

// ---------------------------------------------------------------------------
// WaveSubsystem fused:
//   out = tanh(c@W_mod + b_mod) * (w @ M) + [c z]@W_B + b_B
//   M^T = diag(tanh(A_diag)*0.9) + A_U@A_V^T   (tiny GEMM, bf16)
// Round 5: back to 128x128 tile (R4's 128x64 regressed: barrier-drain per
// MFMA worsened). BK=64 macro-steps: one vmcnt-drain + barrier pair per 64
// k-depth (was 32) -> 96 drains instead of 192, staged bytes unchanged,
// 32 MFMA/wave per drain. LDS 32 KB (2 blocks/CU still fits, grid was the
// residency cap anyway). XOR swizzle adapted to [row][slot^row&7] layout.
// ---------------------------------------------------------------------------

#define DEV __device__ __forceinline__

typedef __bf16 v8bf __attribute__((ext_vector_type(8)));
typedef __bf16 v4bf __attribute__((ext_vector_type(4)));
typedef float  v4f  __attribute__((ext_vector_type(4)));

typedef __attribute__((address_space(1))) const unsigned int* as1_cuint_ptr;
typedef __attribute__((address_space(3))) unsigned int*       as3_uint_ptr;

DEV void async16(const void* g, void* l) {
  __builtin_amdgcn_global_load_lds(
      (as1_cuint_ptr)(unsigned long long)g,
      (as3_uint_ptr)(unsigned long long)l,
      16, 0, 0);
}

DEV float tanh_fast(float x) {
  x = fminf(15.f, fmaxf(-15.f, x));
  float e = __expf(2.f * x);
  return (e - 1.f) / (e + 1.f);
}

// --------------------------- prep kernel -----------------------------------
__global__ void prep(const float* __restrict__ w, const float* __restrict__ z,
                     const float* __restrict__ c, const float* __restrict__ au,
                     const float* __restrict__ av,
                     const float* __restrict__ Wmod, const float* __restrict__ WB,
                     __bf16* __restrict__ wb, __bf16* __restrict__ zb,
                     __bf16* __restrict__ cb, __bf16* __restrict__ aub,
                     __bf16* __restrict__ avb,
                     __bf16* __restrict__ Wmodt, __bf16* __restrict__ WBt) {
  __shared__ float t[32][33];
  int b = blockIdx.x;
  if (b < 22528) {
    const float* src; __bf16* dst; int off;
    if (b < 8192)        { src = w;  dst = wb;  off = b; }
    else if (b < 16384)  { src = z;  dst = zb;  off = b - 8192; }
    else if (b < 20480)  { src = c;  dst = cb;  off = b - 16384; }
    else if (b < 21504)  { src = au; dst = aub; off = b - 20480; }
    else                 { src = av; dst = avb; off = b - 21504; }
    size_t i = (size_t)off * 1024 + (size_t)threadIdx.x * 4;
    float4 v = *reinterpret_cast<const float4*>(src + i);
    v4bf o;
    o.x = (__bf16)v.x; o.y = (__bf16)v.y; o.z = (__bf16)v.z; o.w = (__bf16)v.w;
    *reinterpret_cast<v4bf*>(dst + i) = o;
    return;
  }
  b -= 22528;
  const float* src; __bf16* dst; int R;
  if (b < 2048) { src = Wmod; dst = Wmodt; R = 1024; }
  else          { b -= 2048; src = WB; dst = WBt; R = 3072; }
  const int c0 = (b & 63) * 32, r0 = (b >> 6) * 32;
  const int C = 2048;
  const int tx = threadIdx.x & 31, ty = threadIdx.x >> 5;
#pragma unroll
  for (int rr = 0; rr < 32; rr += 8)
    t[ty + rr][tx] = src[(size_t)(r0 + ty + rr) * C + c0 + tx];
  __syncthreads();
#pragma unroll
  for (int rr = 0; rr < 32; rr += 8)
    dst[(size_t)(c0 + ty + rr) * R + r0 + tx] = (__bf16)t[tx][ty + rr];
}

// ---------------------- Mt builder GEMM ------------------------------------
// Mt[m][n'] = (A_U @ A_V^T)[m][n'] + (m==n' ? tanh(A_diag[m])*0.9 : 0)
__global__ __launch_bounds__(256, 2) void gemm_mt(
    const __bf16* __restrict__ A0, const __bf16* __restrict__ Bt,
    int N, int K, __bf16* __restrict__ out, const float* __restrict__ A_diag) {
  __shared__ __align__(16) __bf16 As[128 * 32];
  __shared__ __align__(16) __bf16 Bs[128 * 32];

  const int tid = threadIdx.x, lane = tid & 63, wid = tid >> 6;
  const int wm = wid >> 1, wn = wid & 1, l16 = lane & 15, quad = lane >> 4;
  const int m0 = blockIdx.y * 128, n0 = blockIdx.x * 128;
  const int sg_row = lane >> 2;
  const int sk = ((lane & 3) ^ ((lane >> 3) & 3)) * 8;
  const int qs = quad ^ ((l16 >> 1) & 3);

  v4f acc[4][4];
#pragma unroll
  for (int i = 0; i < 4; ++i)
#pragma unroll
    for (int j = 0; j < 4; ++j) { v4f zz = {0,0,0,0}; acc[i][j] = zz; }

  for (int k0 = 0; k0 < K; k0 += 32) {
    __syncthreads();
#pragma unroll
    for (int t = 0; t < 2; ++t) {
      const int chunk = wid * 2 + t;
      const int row = chunk * 16 + sg_row;
      async16((const void*)(A0 + (size_t)(m0 + row) * K + k0 + sk),
              (void*)&As[chunk * 512 + lane * 8]);
      async16((const void*)(Bt + (size_t)(n0 + row) * K + k0 + sk),
              (void*)&Bs[chunk * 512 + lane * 8]);
    }
    __syncthreads();
    const v8bf* Ap = reinterpret_cast<const v8bf*>(As);
    const v8bf* Bp = reinterpret_cast<const v8bf*>(Bs);
    v8bf a[4], b[4];
#pragma unroll
    for (int i = 0; i < 4; ++i) a[i] = Ap[(wm * 64 + i * 16 + l16) * 4 + qs];
#pragma unroll
    for (int j = 0; j < 4; ++j) b[j] = Bp[(wn * 64 + j * 16 + l16) * 4 + qs];
#pragma unroll
    for (int i = 0; i < 4; ++i)
#pragma unroll
      for (int j = 0; j < 4; ++j)
        acc[i][j] = __builtin_amdgcn_mfma_f32_16x16x32_bf16(a[i], b[j],
                                                            acc[i][j], 0, 0, 0);
  }

  const int mBase = m0 + wm * 64 + quad * 4;
  const int nBase = n0 + wn * 64 + l16;
#pragma unroll
  for (int j = 0; j < 4; ++j) {
    const int n = nBase + j * 16;
#pragma unroll
    for (int i = 0; i < 4; ++i)
#pragma unroll
      for (int r = 0; r < 4; ++r) {
        const int m = mBase + i * 16 + r;
        float v = acc[i][j][r];
        if (m == n) v += tanh_fast(A_diag[m]) * 0.9f;
        out[(size_t)m * N + n] = (__bf16)v;
      }
  }
}

// ---------------------- fused main kernel ----------------------------------
// 128x128 tile, 4 waves (64x64 each), BK=64 macro-steps.
// LDS layout: [row][slot] with 8 16B-slots per row (64 k); slot j of row r
// stored at j^(r&7). Staging k-offset and read slot fold to lane constants.
__global__ __launch_bounds__(256, 2) void fused_main(
    const __bf16* __restrict__ c, const __bf16* __restrict__ z,
    const __bf16* __restrict__ w, const __bf16* __restrict__ Wmodt,
    const __bf16* __restrict__ Mt, const __bf16* __restrict__ WBt,
    const float* __restrict__ b_mod, const float* __restrict__ b_B,
    float* __restrict__ out) {
  constexpr int DC = 1024, DW = 2048, KB = 3072;
  __shared__ __align__(16) __bf16 As[128 * 64];  // 16 KB
  __shared__ __align__(16) __bf16 Bs[128 * 64];  // 16 KB

  const int tid = threadIdx.x, lane = tid & 63, wid = tid >> 6;
  const int wm = wid >> 1, wn = wid & 1, l16 = lane & 15, quad = lane >> 4;
  const int m0 = blockIdx.y * 128;  // batch
  const int n0 = blockIdx.x * 128;  // d_w
  // staging: wave wid covers rows [wid*32, wid*32+32), 4 instrs x 8 rows.
  const int lrow = lane >> 3;            // 0..7 row within instr
  const int skel = ((lane & 7) ^ (lrow & 7)) * 8;  // swizzled k elem offset
  // read: slot for substep s, quad q, row r: (s*4+q)^(r&7); r&7 == l16&7.
  const int qs0 = (quad) ^ (l16 & 7);
  const int qs1 = (4 + quad) ^ (l16 & 7);

  v4f acc[4][4];
#pragma unroll
  for (int i = 0; i < 4; ++i)
#pragma unroll
    for (int j = 0; j < 4; ++j) { v4f zz = {0,0,0,0}; acc[i][j] = zz; }

  // one BK=64 macro-step
  auto kstep = [&](const __bf16* gA, size_t lda, const __bf16* gB, size_t ldb,
                   int kA, int kB) {
    __syncthreads();
#pragma unroll
    for (int t = 0; t < 4; ++t) {
      const int row = wid * 32 + t * 8 + lrow;
      async16((const void*)(gA + (size_t)(m0 + row) * lda + kA + skel),
              (void*)&As[row * 64 + (lane & 7) * 8]);
      async16((const void*)(gB + (size_t)(n0 + row) * ldb + kB + skel),
              (void*)&Bs[row * 64 + (lane & 7) * 8]);
    }
    __syncthreads();
    const v8bf* Ap = reinterpret_cast<const v8bf*>(As);
    const v8bf* Bp = reinterpret_cast<const v8bf*>(Bs);
    v8bf a[4], b[4];
    // substep 0 (k 0..31)
#pragma unroll
    for (int i = 0; i < 4; ++i) a[i] = Ap[(wm * 64 + i * 16 + l16) * 8 + qs0];
#pragma unroll
    for (int j = 0; j < 4; ++j) b[j] = Bp[(wn * 64 + j * 16 + l16) * 8 + qs0];
#pragma unroll
    for (int i = 0; i < 4; ++i)
#pragma unroll
      for (int j = 0; j < 4; ++j)
        acc[i][j] = __builtin_amdgcn_mfma_f32_16x16x32_bf16(a[i], b[j],
                                                            acc[i][j], 0, 0, 0);
    // substep 1 (k 32..63)
#pragma unroll
    for (int i = 0; i < 4; ++i) a[i] = Ap[(wm * 64 + i * 16 + l16) * 8 + qs1];
#pragma unroll
    for (int j = 0; j < 4; ++j) b[j] = Bp[(wn * 64 + j * 16 + l16) * 8 + qs1];
#pragma unroll
    for (int i = 0; i < 4; ++i)
#pragma unroll
      for (int j = 0; j < 4; ++j)
        acc[i][j] = __builtin_amdgcn_mfma_f32_16x16x32_bf16(a[i], b[j],
                                                            acc[i][j], 0, 0, 0);
  };

  const int nBase = n0 + wn * 64 + l16;

  // ---- phase A: mod = tanh(c @ Wmodt + b_mod) ----
  for (int k0 = 0; k0 < DC; k0 += 64) kstep(c, DC, Wmodt, DC, k0, k0);

  v4f mod_s[4][4];
#pragma unroll
  for (int j = 0; j < 4; ++j) {
    const float bn = b_mod[nBase + j * 16];
#pragma unroll
    for (int i = 0; i < 4; ++i) {
#pragma unroll
      for (int r = 0; r < 4; ++r)
        mod_s[i][j][r] = tanh_fast(acc[i][j][r] + bn);
      v4f zz = {0,0,0,0};
      acc[i][j] = zz;
    }
  }

  // ---- phase B: acc = w @ Mt ----
  for (int k0 = 0; k0 < DW; k0 += 64) kstep(w, DW, Mt, DW, k0, k0);

#pragma unroll
  for (int i = 0; i < 4; ++i)
#pragma unroll
    for (int j = 0; j < 4; ++j) acc[i][j] *= mod_s[i][j];

  // ---- phase C: acc += [c z] @ WBt ----
  for (int k0 = 0; k0 < DC; k0 += 64) kstep(c, DC, WBt, KB, k0, k0);
  for (int k0 = DC; k0 < KB; k0 += 64) kstep(z, DW, WBt, KB, k0 - DC, k0);

  // ---- epilogue ----
  const int mBase = m0 + wm * 64 + quad * 4;
#pragma unroll
  for (int j = 0; j < 4; ++j) {
    const int n = nBase + j * 16;
    const float bn = b_B[n];
#pragma unroll
    for (int i = 0; i < 4; ++i)
#pragma unroll
      for (int r = 0; r < 4; ++r) {
        const int m = mBase + i * 16 + r;
        out[(size_t)m * DW + n] = acc[i][j][r] + bn;
      }
  }
}

// ------------------------------ launch -------------------------------------

extern "C" void kernel_launch(void* const* d_in, const int* in_sizes, int n_in,
                              void* d_out, int out_size, void* d_ws,
                              size_t ws_size, hipStream_t stream) {
  const float* w_prev = (const float*)d_in[0];
  const float* z_t    = (const float*)d_in[1];
  const float* c_t    = (const float*)d_in[2];
  const float* A_diag = (const float*)d_in[3];
  const float* A_U    = (const float*)d_in[4];
  const float* A_V    = (const float*)d_in[5];
  const float* W_mod  = (const float*)d_in[6];
  const float* b_mod  = (const float*)d_in[7];
  const float* W_B    = (const float*)d_in[8];
  const float* b_B    = (const float*)d_in[9];

  constexpr int Bsz = 4096, DW = 2048, RK = 512;
  const size_t MB = 1ull << 20;
  char* ws = (char*)d_ws;
  __bf16* w_bf  = (__bf16*)(ws + 0);        // 16 MB
  __bf16* z_bf  = (__bf16*)(ws + 16 * MB);  // 16 MB
  __bf16* c_bf  = (__bf16*)(ws + 32 * MB);  //  8 MB
  __bf16* AU_bf = (__bf16*)(ws + 40 * MB);  //  2 MB  [2048][512]
  __bf16* AV_bf = (__bf16*)(ws + 42 * MB);  //  2 MB  [2048][512]
  __bf16* Wmodt = (__bf16*)(ws + 44 * MB);  //  4 MB  [2048][1024]
  __bf16* WBt   = (__bf16*)(ws + 48 * MB);  // 12 MB  [2048][3072]
  __bf16* Mt    = (__bf16*)(ws + 60 * MB);  //  8 MB  [2048][2048]

  prep<<<30720, 256, 0, stream>>>(w_prev, z_t, c_t, A_U, A_V, W_mod, W_B,
                                  w_bf, z_bf, c_bf, AU_bf, AV_bf, Wmodt, WBt);

  gemm_mt<<<dim3(DW / 128, DW / 128), 256, 0, stream>>>(AU_bf, AV_bf, DW, RK,
                                                        Mt, A_diag);

  fused_main<<<dim3(DW / 128, Bsz / 128), 256, 0, stream>>>(
      c_bf, z_bf, w_bf, Wmodt, Mt, WBt, b_mod, b_B, (float*)d_out);
}

// Round 6
// 282.854 us; speedup vs baseline: 1.1861x; 1.0221x over previous
//
#include <hip/hip_runtime.h>

// ---------------------------------------------------------------------------
// WaveSubsystem fused:
//   out = tanh(c@W_mod + b_mod) * (w @ M) + [c z]@W_B + b_B
//   M^T = diag(tanh(A_diag)*0.9) + A_U@A_V^T   (tiny GEMM, bf16)
// Round 6: BK=128 macro-steps (48 vmcnt-drains, was 96 at BK=64; R4->R5->R6
// ladder shows the kernel is barrier-drain-bound). LDS 64 KB, 2 blocks/CU
// (grid 512 was already the residency cap). 16-slot XOR swizzle:
// LDS slot j of row r holds global slot j^(r&15); read slot (s*4+quad)^l16.
// Bank-balanced (each 4-bank group hit exactly 8x per b128 = the floor).
// ---------------------------------------------------------------------------

#define DEV __device__ __forceinline__

typedef __bf16 v8bf __attribute__((ext_vector_type(8)));
typedef __bf16 v4bf __attribute__((ext_vector_type(4)));
typedef float  v4f  __attribute__((ext_vector_type(4)));

typedef __attribute__((address_space(1))) const unsigned int* as1_cuint_ptr;
typedef __attribute__((address_space(3))) unsigned int*       as3_uint_ptr;

DEV void async16(const void* g, void* l) {
  __builtin_amdgcn_global_load_lds(
      (as1_cuint_ptr)(unsigned long long)g,
      (as3_uint_ptr)(unsigned long long)l,
      16, 0, 0);
}

DEV float tanh_fast(float x) {
  x = fminf(15.f, fmaxf(-15.f, x));
  float e = __expf(2.f * x);
  return (e - 1.f) / (e + 1.f);
}

// --------------------------- prep kernel -----------------------------------
__global__ void prep(const float* __restrict__ w, const float* __restrict__ z,
                     const float* __restrict__ c, const float* __restrict__ au,
                     const float* __restrict__ av,
                     const float* __restrict__ Wmod, const float* __restrict__ WB,
                     __bf16* __restrict__ wb, __bf16* __restrict__ zb,
                     __bf16* __restrict__ cb, __bf16* __restrict__ aub,
                     __bf16* __restrict__ avb,
                     __bf16* __restrict__ Wmodt, __bf16* __restrict__ WBt) {
  __shared__ float t[32][33];
  int b = blockIdx.x;
  if (b < 22528) {
    const float* src; __bf16* dst; int off;
    if (b < 8192)        { src = w;  dst = wb;  off = b; }
    else if (b < 16384)  { src = z;  dst = zb;  off = b - 8192; }
    else if (b < 20480)  { src = c;  dst = cb;  off = b - 16384; }
    else if (b < 21504)  { src = au; dst = aub; off = b - 20480; }
    else                 { src = av; dst = avb; off = b - 21504; }
    size_t i = (size_t)off * 1024 + (size_t)threadIdx.x * 4;
    float4 v = *reinterpret_cast<const float4*>(src + i);
    v4bf o;
    o.x = (__bf16)v.x; o.y = (__bf16)v.y; o.z = (__bf16)v.z; o.w = (__bf16)v.w;
    *reinterpret_cast<v4bf*>(dst + i) = o;
    return;
  }
  b -= 22528;
  const float* src; __bf16* dst; int R;
  if (b < 2048) { src = Wmod; dst = Wmodt; R = 1024; }
  else          { b -= 2048; src = WB; dst = WBt; R = 3072; }
  const int c0 = (b & 63) * 32, r0 = (b >> 6) * 32;
  const int C = 2048;
  const int tx = threadIdx.x & 31, ty = threadIdx.x >> 5;
#pragma unroll
  for (int rr = 0; rr < 32; rr += 8)
    t[ty + rr][tx] = src[(size_t)(r0 + ty + rr) * C + c0 + tx];
  __syncthreads();
#pragma unroll
  for (int rr = 0; rr < 32; rr += 8)
    dst[(size_t)(c0 + ty + rr) * R + r0 + tx] = (__bf16)t[tx][ty + rr];
}

// ---------------------- Mt builder GEMM ------------------------------------
// Mt[m][n'] = (A_U @ A_V^T)[m][n'] + (m==n' ? tanh(A_diag[m])*0.9 : 0)
__global__ __launch_bounds__(256, 2) void gemm_mt(
    const __bf16* __restrict__ A0, const __bf16* __restrict__ Bt,
    int N, int K, __bf16* __restrict__ out, const float* __restrict__ A_diag) {
  __shared__ __align__(16) __bf16 As[128 * 32];
  __shared__ __align__(16) __bf16 Bs[128 * 32];

  const int tid = threadIdx.x, lane = tid & 63, wid = tid >> 6;
  const int wm = wid >> 1, wn = wid & 1, l16 = lane & 15, quad = lane >> 4;
  const int m0 = blockIdx.y * 128, n0 = blockIdx.x * 128;
  const int sg_row = lane >> 2;
  const int sk = ((lane & 3) ^ ((lane >> 3) & 3)) * 8;
  const int qs = quad ^ ((l16 >> 1) & 3);

  v4f acc[4][4];
#pragma unroll
  for (int i = 0; i < 4; ++i)
#pragma unroll
    for (int j = 0; j < 4; ++j) { v4f zz = {0,0,0,0}; acc[i][j] = zz; }

  for (int k0 = 0; k0 < K; k0 += 32) {
    __syncthreads();
#pragma unroll
    for (int t = 0; t < 2; ++t) {
      const int chunk = wid * 2 + t;
      const int row = chunk * 16 + sg_row;
      async16((const void*)(A0 + (size_t)(m0 + row) * K + k0 + sk),
              (void*)&As[chunk * 512 + lane * 8]);
      async16((const void*)(Bt + (size_t)(n0 + row) * K + k0 + sk),
              (void*)&Bs[chunk * 512 + lane * 8]);
    }
    __syncthreads();
    const v8bf* Ap = reinterpret_cast<const v8bf*>(As);
    const v8bf* Bp = reinterpret_cast<const v8bf*>(Bs);
    v8bf a[4], b[4];
#pragma unroll
    for (int i = 0; i < 4; ++i) a[i] = Ap[(wm * 64 + i * 16 + l16) * 4 + qs];
#pragma unroll
    for (int j = 0; j < 4; ++j) b[j] = Bp[(wn * 64 + j * 16 + l16) * 4 + qs];
#pragma unroll
    for (int i = 0; i < 4; ++i)
#pragma unroll
      for (int j = 0; j < 4; ++j)
        acc[i][j] = __builtin_amdgcn_mfma_f32_16x16x32_bf16(a[i], b[j],
                                                            acc[i][j], 0, 0, 0);
  }

  const int mBase = m0 + wm * 64 + quad * 4;
  const int nBase = n0 + wn * 64 + l16;
#pragma unroll
  for (int j = 0; j < 4; ++j) {
    const int n = nBase + j * 16;
#pragma unroll
    for (int i = 0; i < 4; ++i)
#pragma unroll
      for (int r = 0; r < 4; ++r) {
        const int m = mBase + i * 16 + r;
        float v = acc[i][j][r];
        if (m == n) v += tanh_fast(A_diag[m]) * 0.9f;
        out[(size_t)m * N + n] = (__bf16)v;
      }
  }
}

// ---------------------- fused main kernel ----------------------------------
// 128x128 tile, 4 waves (64x64 each), BK=128 macro-steps, LDS 64 KB.
__global__ __launch_bounds__(256, 2) void fused_main(
    const __bf16* __restrict__ c, const __bf16* __restrict__ z,
    const __bf16* __restrict__ w, const __bf16* __restrict__ Wmodt,
    const __bf16* __restrict__ Mt, const __bf16* __restrict__ WBt,
    const float* __restrict__ b_mod, const float* __restrict__ b_B,
    float* __restrict__ out) {
  constexpr int DC = 1024, DW = 2048, KB = 3072;
  __shared__ __align__(16) __bf16 As[128 * 128];  // 32 KB
  __shared__ __align__(16) __bf16 Bs[128 * 128];  // 32 KB

  const int tid = threadIdx.x, lane = tid & 63, wid = tid >> 6;
  const int wm = wid >> 1, wn = wid & 1, l16 = lane & 15, quad = lane >> 4;
  const int m0 = blockIdx.y * 128;  // batch
  const int n0 = blockIdx.x * 128;  // d_w
  const int r4  = lane >> 4;   // 0..3 row-within-instr
  const int s16 = lane & 15;   // LDS slot index

  v4f acc[4][4];
#pragma unroll
  for (int i = 0; i < 4; ++i)
#pragma unroll
    for (int j = 0; j < 4; ++j) { v4f zz = {0,0,0,0}; acc[i][j] = zz; }

  // one BK=128 macro-step: stage 128 rows x 128 k of A and B, then 4 MFMA
  // substeps. Staging: wave wid covers rows [wid*32, wid*32+32), 8 instrs x
  // 4 rows each; LDS slot s16 of row r gets global slot s16^(r&15).
  auto kstep = [&](const __bf16* gA, size_t lda, const __bf16* gB, size_t ldb,
                   int kA, int kB) {
    __syncthreads();
#pragma unroll
    for (int t = 0; t < 8; ++t) {
      const int row = wid * 32 + t * 4 + r4;
      const int gk = (s16 ^ (row & 15)) * 8;  // global k elem offset
      async16((const void*)(gA + (size_t)(m0 + row) * lda + kA + gk),
              (void*)&As[row * 128 + s16 * 8]);
      async16((const void*)(gB + (size_t)(n0 + row) * ldb + kB + gk),
              (void*)&Bs[row * 128 + s16 * 8]);
    }
    __syncthreads();
    const v8bf* Ap = reinterpret_cast<const v8bf*>(As);
    const v8bf* Bp = reinterpret_cast<const v8bf*>(Bs);
#pragma unroll
    for (int s = 0; s < 4; ++s) {
      const int rs = (s * 4 + quad) ^ l16;  // swizzled read slot
      v8bf a[4], b[4];
#pragma unroll
      for (int i = 0; i < 4; ++i)
        a[i] = Ap[(wm * 64 + i * 16 + l16) * 16 + rs];
#pragma unroll
      for (int j = 0; j < 4; ++j)
        b[j] = Bp[(wn * 64 + j * 16 + l16) * 16 + rs];
#pragma unroll
      for (int i = 0; i < 4; ++i)
#pragma unroll
        for (int j = 0; j < 4; ++j)
          acc[i][j] = __builtin_amdgcn_mfma_f32_16x16x32_bf16(
              a[i], b[j], acc[i][j], 0, 0, 0);
    }
  };

  const int nBase = n0 + wn * 64 + l16;

  // ---- phase A: mod = tanh(c @ Wmodt + b_mod) ----
  for (int k0 = 0; k0 < DC; k0 += 128) kstep(c, DC, Wmodt, DC, k0, k0);

  v4f mod_s[4][4];
#pragma unroll
  for (int j = 0; j < 4; ++j) {
    const float bn = b_mod[nBase + j * 16];
#pragma unroll
    for (int i = 0; i < 4; ++i) {
#pragma unroll
      for (int r = 0; r < 4; ++r)
        mod_s[i][j][r] = tanh_fast(acc[i][j][r] + bn);
      v4f zz = {0,0,0,0};
      acc[i][j] = zz;
    }
  }

  // ---- phase B: acc = w @ Mt ----
  for (int k0 = 0; k0 < DW; k0 += 128) kstep(w, DW, Mt, DW, k0, k0);

#pragma unroll
  for (int i = 0; i < 4; ++i)
#pragma unroll
    for (int j = 0; j < 4; ++j) acc[i][j] *= mod_s[i][j];

  // ---- phase C: acc += [c z] @ WBt ----
  for (int k0 = 0; k0 < DC; k0 += 128) kstep(c, DC, WBt, KB, k0, k0);
  for (int k0 = DC; k0 < KB; k0 += 128) kstep(z, DW, WBt, KB, k0 - DC, k0);

  // ---- epilogue ----
  const int mBase = m0 + wm * 64 + quad * 4;
#pragma unroll
  for (int j = 0; j < 4; ++j) {
    const int n = nBase + j * 16;
    const float bn = b_B[n];
#pragma unroll
    for (int i = 0; i < 4; ++i)
#pragma unroll
      for (int r = 0; r < 4; ++r) {
        const int m = mBase + i * 16 + r;
        out[(size_t)m * DW + n] = acc[i][j][r] + bn;
      }
  }
}

// ------------------------------ launch -------------------------------------

extern "C" void kernel_launch(void* const* d_in, const int* in_sizes, int n_in,
                              void* d_out, int out_size, void* d_ws,
                              size_t ws_size, hipStream_t stream) {
  const float* w_prev = (const float*)d_in[0];
  const float* z_t    = (const float*)d_in[1];
  const float* c_t    = (const float*)d_in[2];
  const float* A_diag = (const float*)d_in[3];
  const float* A_U    = (const float*)d_in[4];
  const float* A_V    = (const float*)d_in[5];
  const float* W_mod  = (const float*)d_in[6];
  const float* b_mod  = (const float*)d_in[7];
  const float* W_B    = (const float*)d_in[8];
  const float* b_B    = (const float*)d_in[9];

  constexpr int Bsz = 4096, DW = 2048, RK = 512;
  const size_t MB = 1ull << 20;
  char* ws = (char*)d_ws;
  __bf16* w_bf  = (__bf16*)(ws + 0);        // 16 MB
  __bf16* z_bf  = (__bf16*)(ws + 16 * MB);  // 16 MB
  __bf16* c_bf  = (__bf16*)(ws + 32 * MB);  //  8 MB
  __bf16* AU_bf = (__bf16*)(ws + 40 * MB);  //  2 MB  [2048][512]
  __bf16* AV_bf = (__bf16*)(ws + 42 * MB);  //  2 MB  [2048][512]
  __bf16* Wmodt = (__bf16*)(ws + 44 * MB);  //  4 MB  [2048][1024]
  __bf16* WBt   = (__bf16*)(ws + 48 * MB);  // 12 MB  [2048][3072]
  __bf16* Mt    = (__bf16*)(ws + 60 * MB);  //  8 MB  [2048][2048]

  prep<<<30720, 256, 0, stream>>>(w_prev, z_t, c_t, A_U, A_V, W_mod, W_B,
                                  w_bf, z_bf, c_bf, AU_bf, AV_bf, Wmodt, WBt);

  gemm_mt<<<dim3(DW / 128, DW / 128), 256, 0, stream>>>(AU_bf, AV_bf, DW, RK,
                                                        Mt, A_diag);

  fused_main<<<dim3(DW / 128, Bsz / 128), 256, 0, stream>>>(
      c_bf, z_bf, w_bf, Wmodt, Mt, WBt, b_mod, b_B, (float*)d_out);
}